// Round 1
// baseline (405.361 us; speedup 1.0000x reference)
//
#include <hip/hip_runtime.h>
#include <stdint.h>

#define N_NODES_C 20000
#define N_EDGES_C 320000
#define NUM_RELS_C 16
#define FEAT_C 256
#define BM 128
#define BN 128
#define BK 32
#define MAX_TILES ((N_EDGES_C / BM) + NUM_RELS_C)  // 2516

typedef __bf16 bf16_t;
typedef __bf16 bf16x8 __attribute__((ext_vector_type(8)));
typedef __bf16 bf16x4 __attribute__((ext_vector_type(4)));
typedef float f32x4 __attribute__((ext_vector_type(4)));

struct TileEnt { int rel; int row_start; int rows; };

__device__ __forceinline__ void async_load16(const void* g, void* l) {
  __builtin_amdgcn_global_load_lds(
      (__attribute__((address_space(1))) void*)const_cast<void*>(g),
      (__attribute__((address_space(3))) void*)l, 16, 0, 0);
}

// ---- h fp32 -> bf16 (row-major unchanged) ----
__global__ void cvt_h_kernel(const float* __restrict__ h, bf16_t* __restrict__ hB) {
  int i = (blockIdx.x * blockDim.x + threadIdx.x) * 4;
  float4 v = *(const float4*)(h + i);
  bf16x4 o = { (bf16_t)v.x, (bf16_t)v.y, (bf16_t)v.z, (bf16_t)v.w };
  *(bf16x4*)(hB + i) = o;
}

// ---- W [r][in][out] fp32 -> Wt [r][out][in] bf16 (transpose so B-frags are contiguous in k) ----
__global__ void cvt_w_kernel(const float* __restrict__ W, bf16_t* __restrict__ Wt) {
  int g = blockIdx.x * blockDim.x + threadIdx.x;
  int i = g & 255;
  int o = (g >> 8) & 255;
  int r = g >> 16;
  Wt[(r << 16) + (o << 8) + i] = (bf16_t)W[(r << 16) + (i << 8) + o];
}

// ---- histogram of rel types (LDS-aggregated) ----
__global__ void hist_kernel(const int* __restrict__ rel, int* __restrict__ gcnt) {
  __shared__ int l[NUM_RELS_C];
  int t = threadIdx.x;
  if (t < NUM_RELS_C) l[t] = 0;
  __syncthreads();
  int e = blockIdx.x * blockDim.x + t;
  if (e < N_EDGES_C) atomicAdd(&l[rel[e]], 1);
  __syncthreads();
  if (t < NUM_RELS_C && l[t] > 0) atomicAdd(&gcnt[t], l[t]);
}

// ---- prefix sums + tile table (single block) ----
__global__ void scan_kernel(const int* __restrict__ cnt, int* __restrict__ cur,
                            int* __restrict__ ntl, TileEnt* __restrict__ table) {
  __shared__ int starts[NUM_RELS_C];
  __shared__ int counts[NUM_RELS_C];
  __shared__ int tstart[NUM_RELS_C + 1];
  int t = threadIdx.x;
  if (t == 0) {
    int acc = 0, tacc = 0;
    for (int r = 0; r < NUM_RELS_C; ++r) {
      counts[r] = cnt[r];
      starts[r] = acc; acc += counts[r];
      tstart[r] = tacc; tacc += (counts[r] + BM - 1) / BM;
    }
    tstart[NUM_RELS_C] = tacc;
    *ntl = tacc;
  }
  __syncthreads();
  if (t < NUM_RELS_C) cur[t] = starts[t];
  int T = tstart[NUM_RELS_C];
  for (int i = t; i < T; i += blockDim.x) {
    int r = 0;
    while (i >= tstart[r + 1]) ++r;
    int lt = i - tstart[r];
    TileEnt e;
    e.rel = r;
    e.row_start = starts[r] + lt * BM;
    int rem = counts[r] - lt * BM;
    e.rows = rem < BM ? rem : BM;
    table[i] = e;
  }
}

// ---- scatter edge ids into rel buckets (block-aggregated reservation) ----
__global__ void bucket_kernel(const int* __restrict__ rel, int* __restrict__ cur,
                              int* __restrict__ perm) {
  __shared__ int lcnt[NUM_RELS_C];
  __shared__ int lbase[NUM_RELS_C];
  int t = threadIdx.x;
  if (t < NUM_RELS_C) lcnt[t] = 0;
  __syncthreads();
  int e = blockIdx.x * blockDim.x + t;
  int r = 0, lpos = 0;
  if (e < N_EDGES_C) { r = rel[e]; lpos = atomicAdd(&lcnt[r], 1); }
  __syncthreads();
  if (t < NUM_RELS_C && lcnt[t] > 0) lbase[t] = atomicAdd(&cur[t], lcnt[t]);
  __syncthreads();
  if (e < N_EDGES_C) perm[lbase[r] + lpos] = e;
}

// ---- main: per-rel-tile gathered GEMM + fp32 atomic scatter ----
// Tile: BM=128 edges x BN=128 out-features, K=256 in steps of BK=32.
// 4 waves in 2x2; each wave 64x64 via 4x4 grid of 16x16x32 bf16 MFMAs.
// A staged via global_load_lds(16B): LDS slot is fixed tid*16; XOR swizzle
// (chunk ^= (row>>1)&3) is applied on the GLOBAL address so frag ds_read_b128
// lands at <=2-way bank aliasing (free, m136) without breaking the lane-
// contiguous LDS destination requirement of global_load_lds (m104/m108).
__global__ __launch_bounds__(256) void gemm_scatter_kernel(
    const bf16_t* __restrict__ hB, const bf16_t* __restrict__ Wt,
    const int* __restrict__ perm, const int* __restrict__ srcA,
    const int* __restrict__ dstA, const float* __restrict__ normA,
    const int* __restrict__ ntl, const TileEnt* __restrict__ table,
    float* __restrict__ out) {
  int tb = blockIdx.x;
  if (tb >= *ntl) return;
  TileEnt te = table[tb];
  int n0 = blockIdx.y * BN;

  __shared__ bf16_t Asm[BM * BK];   // 8 KB
  __shared__ bf16_t Bsm[BN * BK];   // 8 KB
  __shared__ int src_l[BM];
  __shared__ int dst_l[BM];
  __shared__ float norm_l[BM];

  int tid = threadIdx.x;
  if (tid < BM) {
    bool valid = tid < te.rows;
    int e = valid ? perm[te.row_start + tid] : 0;
    src_l[tid] = valid ? srcA[e] : 0;
    dst_l[tid] = valid ? dstA[e] : 0;
    norm_l[tid] = valid ? normA[e] : 0.0f;
  }
  __syncthreads();

  // staging mapping: thread -> (row = tid/4 [+64 second pass], phys chunk = tid&3)
  int lrow = tid >> 2;
  int pch = tid & 3;
  int rA0 = lrow, rA1 = lrow + 64;
  int lc0 = pch ^ ((rA0 >> 1) & 3);   // logical k-chunk held in this phys slot
  int lc1 = pch ^ ((rA1 >> 1) & 3);
  const char* gA0 = (const char*)(hB + (size_t)src_l[rA0] * FEAT_C) + lc0 * 16;
  const char* gA1 = (const char*)(hB + (size_t)src_l[rA1] * FEAT_C) + lc1 * 16;
  const char* gB0 = (const char*)(Wt + ((size_t)te.rel * 256 + n0 + rA0) * FEAT_C) + lc0 * 16;
  const char* gB1 = (const char*)(Wt + ((size_t)te.rel * 256 + n0 + rA1) * FEAT_C) + lc1 * 16;

  int wave = tid >> 6;
  char* aB0 = (char*)Asm + wave * 1024;
  char* aB1 = (char*)Asm + 4096 + wave * 1024;
  char* bB0 = (char*)Bsm + wave * 1024;
  char* bB1 = (char*)Bsm + 4096 + wave * 1024;

  int lane = tid & 63;
  int lq = lane >> 4;      // k-quad
  int lr = lane & 15;      // m (A) / n (B) / col (C)
  int wm = (wave >> 1) * 64;
  int wn = (wave & 1) * 64;
  int pc8 = (lq ^ ((lr >> 1) & 3)) * 8;  // phys chunk offset in elements

  f32x4 acc[4][4] = {};

  for (int kk = 0; kk < 8; ++kk) {
    int kb = kk * 64;  // 32 bf16 = 64 B per K step
    async_load16(gA0 + kb, aB0);
    async_load16(gA1 + kb, aB1);
    async_load16(gB0 + kb, bB0);
    async_load16(gB1 + kb, bB1);
    __syncthreads();   // vmcnt(0) drain + barrier: tiles visible to all waves
    bf16x8 af[4], bfr[4];
#pragma unroll
    for (int mt = 0; mt < 4; ++mt) {
      int row = wm + mt * 16 + lr;
      af[mt] = *(const bf16x8*)&Asm[row * BK + pc8];
    }
#pragma unroll
    for (int nt2 = 0; nt2 < 4; ++nt2) {
      int row = wn + nt2 * 16 + lr;
      bfr[nt2] = *(const bf16x8*)&Bsm[row * BK + pc8];
    }
#pragma unroll
    for (int mt = 0; mt < 4; ++mt)
#pragma unroll
      for (int nt2 = 0; nt2 < 4; ++nt2)
        acc[mt][nt2] = __builtin_amdgcn_mfma_f32_16x16x32_bf16(af[mt], bfr[nt2], acc[mt][nt2], 0, 0, 0);
    __syncthreads();   // all waves done reading before next stage overwrites
  }

  // Epilogue: C/D map col=lane&15, row=quad*4+reg (m89/m91 verified).
#pragma unroll
  for (int mt = 0; mt < 4; ++mt) {
#pragma unroll
    for (int rg = 0; rg < 4; ++rg) {
      int row = wm + mt * 16 + lq * 4 + rg;
      if (row < te.rows) {
        float nrm = norm_l[row];
        long d = dst_l[row];
#pragma unroll
        for (int nt2 = 0; nt2 < 4; ++nt2) {
          int col = n0 + wn + nt2 * 16 + lr;
          atomicAdd(&out[d * FEAT_C + col], acc[mt][nt2][rg] * nrm);
        }
      }
    }
  }
}

extern "C" void kernel_launch(void* const* d_in, const int* in_sizes, int n_in,
                              void* d_out, int out_size, void* d_ws, size_t ws_size,
                              hipStream_t stream) {
  const float* h    = (const float*)d_in[0];
  const float* W    = (const float*)d_in[1];
  const float* norm = (const float*)d_in[2];
  const int*   src  = (const int*)d_in[3];
  const int*   dst  = (const int*)d_in[4];
  const int*   rel  = (const int*)d_in[5];
  float* out = (float*)d_out;

  char* ws = (char*)d_ws;
  bf16_t* hB  = (bf16_t*)ws;                       // 10,240,000 B
  bf16_t* Wt  = (bf16_t*)(ws + 10240000);          //  2,097,152 B
  int* perm   = (int*)(ws + 12337152);             //  1,280,000 B
  int* cnt    = (int*)(ws + 13617152);             // 16 ints
  int* cur    = cnt + 16;                          // 16 ints
  int* ntl    = cnt + 32;                          // 1 int
  TileEnt* table = (TileEnt*)(ws + 13617152 + 33 * 4);

  hipMemsetAsync(out, 0, (size_t)out_size * sizeof(float), stream);
  hipMemsetAsync(cnt, 0, 33 * sizeof(int), stream);
  cvt_h_kernel<<<5000, 256, 0, stream>>>(h, hB);
  cvt_w_kernel<<<4096, 256, 0, stream>>>(W, Wt);
  hist_kernel<<<1250, 256, 0, stream>>>(rel, cnt);
  scan_kernel<<<1, 256, 0, stream>>>(cnt, cur, ntl, table);
  bucket_kernel<<<1250, 256, 0, stream>>>(rel, cur, perm);
  gemm_scatter_kernel<<<dim3(MAX_TILES, 2), 256, 0, stream>>>(
      hB, Wt, perm, src, dst, norm, ntl, table, out);
}

// Round 2
// 304.476 us; speedup vs baseline: 1.3313x; 1.3313x over previous
//
#include <hip/hip_runtime.h>
#include <stdint.h>

#define N_NODES_C 20000
#define N_EDGES_C 320000
#define NUM_RELS_C 16
#define FEAT_C 256

typedef __bf16 bf16_t;
typedef __bf16 bf16x8 __attribute__((ext_vector_type(8)));
typedef __bf16 bf16x4 __attribute__((ext_vector_type(4)));
typedef float f32x4 __attribute__((ext_vector_type(4)));

__device__ __forceinline__ void async_load16(const void* g, void* l) {
  __builtin_amdgcn_global_load_lds(
      (__attribute__((address_space(1))) void*)const_cast<void*>(g),
      (__attribute__((address_space(3))) void*)l, 16, 0, 0);
}

// ---- h fp32 -> bf16 ----
__global__ void cvt_h_kernel(const float* __restrict__ h, bf16_t* __restrict__ hB) {
  int i = (blockIdx.x * blockDim.x + threadIdx.x) * 4;
  float4 v = *(const float4*)(h + i);
  bf16x4 o = { (bf16_t)v.x, (bf16_t)v.y, (bf16_t)v.z, (bf16_t)v.w };
  *(bf16x4*)(hB + i) = o;
}

// ---- W [r][in][out] fp32 -> Wt [r][out][in] bf16 ----
__global__ void cvt_w_kernel(const float* __restrict__ W, bf16_t* __restrict__ Wt) {
  int g = blockIdx.x * blockDim.x + threadIdx.x;
  int i = g & 255;
  int o = (g >> 8) & 255;
  int r = g >> 16;
  Wt[(r << 16) + (o << 8) + i] = (bf16_t)W[(r << 16) + (i << 8) + o];
}

// ---- dst histogram (counts land in dcur) ----
__global__ void hist_dst_kernel(const int* __restrict__ dst, int* __restrict__ dcur) {
  int e = blockIdx.x * blockDim.x + threadIdx.x;
  if (e < N_EDGES_C) atomicAdd(&dcur[dst[e]], 1);
}

// ---- single-block exclusive scan over 20000 counts -> dstart[20001], dcur=start cursors ----
__global__ void scan_dst_kernel(int* __restrict__ dcur, int* __restrict__ dstart) {
  __shared__ int part[256];
  const int CH = 79;  // 256*79 = 20224 >= 20000
  int t = threadIdx.x;
  int base = t * CH;
  int sum = 0;
  for (int i = 0; i < CH; ++i) {
    int idx = base + i;
    if (idx < N_NODES_C) sum += dcur[idx];
  }
  part[t] = sum;
  __syncthreads();
  if (t == 0) {
    int run = 0;
    for (int i = 0; i < 256; ++i) { int v = part[i]; part[i] = run; run += v; }
  }
  __syncthreads();
  int run = part[t];
  for (int i = 0; i < CH; ++i) {
    int idx = base + i;
    if (idx < N_NODES_C) {
      int c = dcur[idx];      // read count
      dstart[idx] = run;
      dcur[idx] = run;        // overwrite with cursor
      run += c;
    }
  }
  if (t == 0) dstart[N_NODES_C] = N_EDGES_C;
}

// ---- bucket edges by dst; store packed (src | rel<<16) + norm ----
__global__ void bucket_dst_kernel(const int* __restrict__ dst, const int* __restrict__ src,
                                  const int* __restrict__ rel, const float* __restrict__ norm,
                                  int* __restrict__ dcur, int* __restrict__ bkt_sr,
                                  float* __restrict__ bkt_nm) {
  int e = blockIdx.x * blockDim.x + threadIdx.x;
  if (e < N_EDGES_C) {
    int pos = atomicAdd(&dcur[dst[e]], 1);
    bkt_sr[pos] = src[e] | (rel[e] << 16);
    bkt_nm[pos] = norm[e];
  }
}

// ---- Phase A: dense T[r][n][:] = hB[n,:] @ Wt[r]^T, stored bf16 in permuted col order ----
// Permutation: position p = 64*(lr4>>4 stuff) -- concretely, value for col
// (n0 + wn + nt2*16 + lr) is stored at position (n0 + wn + lr*4 + nt2).
// Phase B lanes read positions 4l..4l+3 and de-permute on the final out write.
__global__ __launch_bounds__(256) void gemm_t_kernel(
    const bf16_t* __restrict__ hB, const bf16_t* __restrict__ Wt,
    bf16_t* __restrict__ Tb) {
  int m0 = blockIdx.x * 128;
  int n0 = blockIdx.y * 128;
  int r  = blockIdx.z;

  __shared__ bf16_t Asm[128 * 32];   // 8 KB
  __shared__ bf16_t Bsm[128 * 32];   // 8 KB

  int tid = threadIdx.x;
  int lrow = tid >> 2;
  int pch = tid & 3;
  int rA0 = lrow, rA1 = lrow + 64;
  int lc0 = pch ^ ((rA0 >> 1) & 3);
  int lc1 = pch ^ ((rA1 >> 1) & 3);
  int gr0 = m0 + rA0; if (gr0 > N_NODES_C - 1) gr0 = N_NODES_C - 1;
  int gr1 = m0 + rA1; if (gr1 > N_NODES_C - 1) gr1 = N_NODES_C - 1;
  const char* gA0 = (const char*)(hB + (size_t)gr0 * FEAT_C) + lc0 * 16;
  const char* gA1 = (const char*)(hB + (size_t)gr1 * FEAT_C) + lc1 * 16;
  const char* gB0 = (const char*)(Wt + ((size_t)r * 256 + n0 + rA0) * FEAT_C) + lc0 * 16;
  const char* gB1 = (const char*)(Wt + ((size_t)r * 256 + n0 + rA1) * FEAT_C) + lc1 * 16;

  int wave = tid >> 6;
  char* aB0 = (char*)Asm + wave * 1024;
  char* aB1 = (char*)Asm + 4096 + wave * 1024;
  char* bB0 = (char*)Bsm + wave * 1024;
  char* bB1 = (char*)Bsm + 4096 + wave * 1024;

  int lane = tid & 63;
  int lq = lane >> 4;
  int lr = lane & 15;
  int wm = (wave >> 1) * 64;
  int wn = (wave & 1) * 64;
  int pc8 = (lq ^ ((lr >> 1) & 3)) * 8;

  f32x4 acc[4][4] = {};

  for (int kk = 0; kk < 8; ++kk) {
    int kb = kk * 64;
    async_load16(gA0 + kb, aB0);
    async_load16(gA1 + kb, aB1);
    async_load16(gB0 + kb, bB0);
    async_load16(gB1 + kb, bB1);
    __syncthreads();
    bf16x8 af[4], bfr[4];
#pragma unroll
    for (int mt = 0; mt < 4; ++mt) {
      int row = wm + mt * 16 + lr;
      af[mt] = *(const bf16x8*)&Asm[row * 32 + pc8];
    }
#pragma unroll
    for (int nt2 = 0; nt2 < 4; ++nt2) {
      int row = wn + nt2 * 16 + lr;
      bfr[nt2] = *(const bf16x8*)&Bsm[row * 32 + pc8];
    }
#pragma unroll
    for (int mt = 0; mt < 4; ++mt)
#pragma unroll
      for (int nt2 = 0; nt2 < 4; ++nt2)
        acc[mt][nt2] = __builtin_amdgcn_mfma_f32_16x16x32_bf16(af[mt], bfr[nt2], acc[mt][nt2], 0, 0, 0);
    __syncthreads();
  }

  // Epilogue: C/D map col=lane&15, row=quad*4+reg. Pack 4 cols (nt2=0..3, stride 16)
  // into one 8B store at permuted position n0+wn+lr*4.
#pragma unroll
  for (int mt = 0; mt < 4; ++mt) {
#pragma unroll
    for (int rg = 0; rg < 4; ++rg) {
      int row = m0 + wm + mt * 16 + lq * 4 + rg;
      if (row < N_NODES_C) {
        bf16x4 pk = { (bf16_t)acc[mt][0][rg], (bf16_t)acc[mt][1][rg],
                      (bf16_t)acc[mt][2][rg], (bf16_t)acc[mt][3][rg] };
        *(bf16x4*)(Tb + (((size_t)r * N_NODES_C + row) << 8) + n0 + wn + (lr << 2)) = pk;
      }
    }
  }
}

// ---- Phase B: per-dst gather-reduce over CSR, one wave per dst ----
__global__ __launch_bounds__(256) void aggregate_kernel(
    const bf16_t* __restrict__ Tb, const int* __restrict__ dstart,
    const int* __restrict__ bkt_sr, const float* __restrict__ bkt_nm,
    float* __restrict__ out) {
  int tid = threadIdx.x;
  int d = blockIdx.x * 4 + (tid >> 6);
  int lane = tid & 63;
  int p0 = dstart[d];
  int p1 = dstart[d + 1];
  float a0 = 0.f, a1 = 0.f, a2 = 0.f, a3 = 0.f;
  int loff = lane << 2;  // permuted positions 4l..4l+3
  for (int p = p0; p < p1; ++p) {
    int sr = bkt_sr[p];
    float nrm = bkt_nm[p];
    int s = sr & 0xFFFF;
    int r = sr >> 16;
    bf16x4 v = *(const bf16x4*)(Tb + (((size_t)r * N_NODES_C + s) << 8) + loff);
    a0 += (float)v[0] * nrm;
    a1 += (float)v[1] * nrm;
    a2 += (float)v[2] * nrm;
    a3 += (float)v[3] * nrm;
  }
  // De-permute: position 4l+j holds col (4l&192) + j*16 + (l&15)
  float* o = out + (size_t)d * FEAT_C + ((lane << 2) & 192) + (lane & 15);
  o[0]  = a0;
  o[16] = a1;
  o[32] = a2;
  o[48] = a3;
}

extern "C" void kernel_launch(void* const* d_in, const int* in_sizes, int n_in,
                              void* d_out, int out_size, void* d_ws, size_t ws_size,
                              hipStream_t stream) {
  const float* h    = (const float*)d_in[0];
  const float* W    = (const float*)d_in[1];
  const float* norm = (const float*)d_in[2];
  const int*   src  = (const int*)d_in[3];
  const int*   dst  = (const int*)d_in[4];
  const int*   rel  = (const int*)d_in[5];
  float* out = (float*)d_out;

  char* ws = (char*)d_ws;
  bf16_t* hB   = (bf16_t*)ws;                          // 10,240,000 B
  bf16_t* Wt   = (bf16_t*)(ws + 10240000);             //  2,097,152 B
  bf16_t* Tb   = (bf16_t*)(ws + 12337152);             // 163,840,000 B
  int* dstart  = (int*)(ws + 176177152);               // 80,016 B (20001 ints)
  int* dcur    = (int*)(ws + 176257168);               // 80,000 B
  int* bkt_sr  = (int*)(ws + 176337168);               // 1,280,000 B
  float* bkt_nm = (float*)(ws + 177617168);            // 1,280,000 B -> end ~178.9 MB

  hipMemsetAsync(dcur, 0, N_NODES_C * sizeof(int), stream);
  cvt_h_kernel<<<5000, 256, 0, stream>>>(h, hB);
  cvt_w_kernel<<<4096, 256, 0, stream>>>(W, Wt);
  hist_dst_kernel<<<1250, 256, 0, stream>>>(dst, dcur);
  scan_dst_kernel<<<1, 256, 0, stream>>>(dcur, dstart);
  bucket_dst_kernel<<<1250, 256, 0, stream>>>(dst, src, rel, norm, dcur, bkt_sr, bkt_nm);
  gemm_t_kernel<<<dim3(157, 2, 16), 256, 0, stream>>>(hB, Wt, Tb);
  aggregate_kernel<<<5000, 256, 0, stream>>>(Tb, dstart, bkt_sr, bkt_nm, out);
}